// Round 1
// baseline (475.132 us; speedup 1.0000x reference)
//
#include <hip/hip_runtime.h>
#include <math.h>

#define LSEQ 4096
#define DIM 64
#define NBH 64
#define TWO_PI 6.28318530717958647692f

// ws layout (floats):
//   ftpart: [3 tensor][64 bh][2 half][2 reim][64 d][64 m]   -> 3*64*2*8192 = 3,145,728
//   Yp:     [64 bh][128 k][64 d]                            -> 524,288   (off 3145728)
//   BtT:    [128 k][4096 l]                                 -> 524,288   (off 3670016)

// ---------------------------------------------------------------- init basis
__global__ __launch_bounds__(256) void init_basis(float* __restrict__ bt) {
  int u = blockIdx.x * 256 + threadIdx.x;   // < 128*4096
  int k = u >> 12;
  int l = u & 4095;
  int f = k >> 1;
  float ang = (float)((f * l) & 4095) * (TWO_PI / 4096.0f);
  float s, c;
  sincosf(ang, &s, &c);
  bt[u] = (k & 1) ? -s : c;   // even row: cos(2pi f l/N); odd row: -sin(2pi f l/N)
}

// ------------------------------------------------------------- DFT gather
// grid 384 = 3 tensor * 64 bh * 2 half ; block 512
// thread: m = t&63 (mode), g = t>>6 (8 groups of 8 d)
__global__ __launch_bounds__(512) void dft_gather(
    const float* __restrict__ q, const float* __restrict__ k,
    const float* __restrict__ v,
    const int* __restrict__ iq, const int* __restrict__ ik,
    const int* __restrict__ iv, float* __restrict__ ft) {
  int bidx = blockIdx.x;
  int tensor = bidx >> 7;
  int r = bidx & 127;
  int bh = r >> 1, half = r & 1;
  const float* x = (tensor == 0 ? q : tensor == 1 ? k : v) + (size_t)bh * (LSEQ * DIM);
  const int* idx = (tensor == 0 ? iq : tensor == 1 ? ik : iv);

  int t = threadIdx.x;
  int m = t & 63;
  int g = t >> 6;
  int d0 = g * 8;
  int f = idx[m];
  int l0 = half * 2048;

  __shared__ float tile[64 * 64];

  float ar[8], ai[8];
#pragma unroll
  for (int j = 0; j < 8; ++j) { ar[j] = 0.0f; ai[j] = 0.0f; }

  float stepr, stepi;
  {
    float angs = -(TWO_PI / 4096.0f) * (float)f;
    sincosf(angs, &stepi, &stepr);
  }

  for (int ti = 0; ti < 32; ++ti) {
    int lbase = l0 + ti * 64;
    __syncthreads();
    {
      const float4* src = (const float4*)(x + (size_t)lbase * DIM);
      float4* dst = (float4*)tile;
      dst[t] = src[t];
      dst[t + 512] = src[t + 512];
    }
    __syncthreads();
    // resync twiddle exactly (integer phase mod): w = e^{-i*2pi*f*lbase/4096}
    float wr, wi;
    {
      float ang = -(TWO_PI / 4096.0f) * (float)((f * lbase) & 4095);
      sincosf(ang, &wi, &wr);
    }
    for (int i = 0; i < 64; ++i) {
      float4 xa = *(const float4*)&tile[i * 64 + d0];
      float4 xb = *(const float4*)&tile[i * 64 + d0 + 4];
      float xs[8] = {xa.x, xa.y, xa.z, xa.w, xb.x, xb.y, xb.z, xb.w};
#pragma unroll
      for (int j = 0; j < 8; ++j) {
        ar[j] = fmaf(xs[j], wr, ar[j]);
        ai[j] = fmaf(xs[j], wi, ai[j]);
      }
      float nr = wr * stepr - wi * stepi;
      float ni = wr * stepi + wi * stepr;
      wr = nr; wi = ni;
    }
  }
  // store: layout [reim][d][m] per (tensor,bh,half) -> coalesced over m
  float* o = ft + (((size_t)(tensor * NBH + bh)) * 2 + half) * 8192;
#pragma unroll
  for (int j = 0; j < 8; ++j) {
    o[(d0 + j) * 64 + m] = ar[j];
    o[4096 + (d0 + j) * 64 + m] = ai[j];
  }
}

// ------------------------------------------------------------- attention
// grid 256 = 64 bh * 4 mq ; block 256
#define FST 132   // LDS row stride (floats) for [row][d*2+reim] tiles
__global__ __launch_bounds__(256) void attn(const float* __restrict__ ft,
                                            float* __restrict__ yp_g) {
  int bh = blockIdx.x >> 2, mq = blockIdx.x & 3;
  int t = threadIdx.x;

  __shared__ float qf[16 * FST];
  __shared__ float kf[64 * FST];
  __shared__ float vf[64 * FST];
  __shared__ float S[16 * FST];

  const float* qbase = ft + ((size_t)(0 * NBH + bh)) * 2 * 8192;
  const float* kbase = ft + ((size_t)(1 * NBH + bh)) * 2 * 8192;
  const float* vbase = ft + ((size_t)(2 * NBH + bh)) * 2 * 8192;

  // stage k_ft, v_ft: sum the two K-halves; global layout [reim][d][m]
#pragma unroll
  for (int j = 0; j < 8; ++j) {
    int u4 = t + 256 * j;  // < 2048
    float4 a = ((const float4*)kbase)[u4];
    float4 b = ((const float4*)(kbase + 8192))[u4];
    float kvals[4] = {a.x + b.x, a.y + b.y, a.z + b.z, a.w + b.w};
    float4 c = ((const float4*)vbase)[u4];
    float4 d2 = ((const float4*)(vbase + 8192))[u4];
    float vvals[4] = {c.x + d2.x, c.y + d2.y, c.z + d2.z, c.w + d2.w};
    int flat = u4 * 4;
#pragma unroll
    for (int cc = 0; cc < 4; ++cc) {
      int e = flat + cc;
      int reim = e >> 12, dd = (e >> 6) & 63, mm = e & 63;
      kf[mm * FST + 2 * dd + reim] = kvals[cc];
      vf[mm * FST + 2 * dd + reim] = vvals[cc];
    }
  }
  // stage q_ft rows [mq*16, mq*16+16)
#pragma unroll
  for (int j = 0; j < 2; ++j) {
    int u4 = t + 256 * j;  // < 512
    int reim = u4 >> 8, dd = (u4 >> 2) & 63, c4 = u4 & 3;
    int gidx = reim * 1024 + dd * 16 + mq * 4 + c4;
    float4 a = ((const float4*)qbase)[gidx];
    float4 b = ((const float4*)(qbase + 8192))[gidx];
    float qvals[4] = {a.x + b.x, a.y + b.y, a.z + b.z, a.w + b.w};
#pragma unroll
    for (int cc = 0; cc < 4; ++cc)
      qf[(c4 * 4 + cc) * FST + 2 * dd + reim] = qvals[cc];
  }
  __syncthreads();

  int m = t >> 4;
  int n0 = t & 15;
#pragma unroll
  for (int nn = 0; nn < 4; ++nn) {
    int n = n0 + 16 * nn;
    float xr = 0.0f, xi = 0.0f;
    for (int d2 = 0; d2 < 32; ++d2) {  // two complex elements per float4
      float4 qv = *(const float4*)&qf[m * FST + 4 * d2];
      float4 kv = *(const float4*)&kf[n * FST + 4 * d2];
      xr = fmaf(qv.x, kv.x, xr); xr = fmaf(-qv.y, kv.y, xr);
      xi = fmaf(qv.x, kv.y, xi); xi = fmaf(qv.y, kv.x, xi);
      xr = fmaf(qv.z, kv.z, xr); xr = fmaf(-qv.w, kv.w, xr);
      xi = fmaf(qv.z, kv.w, xi); xi = fmaf(qv.w, kv.z, xi);
    }
    float x = xr * 0.125f, y = xi * 0.125f;
    float tr, tim;
    if (fabsf(x) > 40.0f) {
      tr = x > 0.0f ? 1.0f : -1.0f;
      tim = 0.0f;
    } else {
      float sh = sinhf(2.0f * x), ch = coshf(2.0f * x);
      float sn, cn;
      sincosf(2.0f * y, &sn, &cn);
      float den = ch + cn;
      tr = sh / den;
      tim = sn / den;
    }
    S[m * FST + 2 * n] = tr;
    S[m * FST + 2 * n + 1] = tim;
  }
  __syncthreads();

  int d0 = t & 15;  // handles d = 4*d0 .. 4*d0+3
  float ar4[4] = {0, 0, 0, 0}, ai4[4] = {0, 0, 0, 0};
  for (int n = 0; n < 64; ++n) {
    float sr_ = S[m * FST + 2 * n];
    float si_ = S[m * FST + 2 * n + 1];
    float4 va = *(const float4*)&vf[n * FST + 8 * d0];
    float4 vb = *(const float4*)&vf[n * FST + 8 * d0 + 4];
    ar4[0] = fmaf(sr_, va.x, ar4[0]); ar4[0] = fmaf(-si_, va.y, ar4[0]);
    ai4[0] = fmaf(sr_, va.y, ai4[0]); ai4[0] = fmaf(si_, va.x, ai4[0]);
    ar4[1] = fmaf(sr_, va.z, ar4[1]); ar4[1] = fmaf(-si_, va.w, ar4[1]);
    ai4[1] = fmaf(sr_, va.w, ai4[1]); ai4[1] = fmaf(si_, va.z, ai4[1]);
    ar4[2] = fmaf(sr_, vb.x, ar4[2]); ar4[2] = fmaf(-si_, vb.y, ar4[2]);
    ai4[2] = fmaf(sr_, vb.y, ai4[2]); ai4[2] = fmaf(si_, vb.x, ai4[2]);
    ar4[3] = fmaf(sr_, vb.z, ar4[3]); ar4[3] = fmaf(-si_, vb.w, ar4[3]);
    ai4[3] = fmaf(sr_, vb.w, ai4[3]); ai4[3] = fmaf(si_, vb.z, ai4[3]);
  }
  int fbin = mq * 16 + m;
  float cf = (fbin == 0 ? 1.0f : 2.0f) / 4096.0f;
  float4 outr = make_float4(cf * ar4[0], cf * ar4[1], cf * ar4[2], cf * ar4[3]);
  float4 outi = make_float4(cf * ai4[0], cf * ai4[1], cf * ai4[2], cf * ai4[3]);
  *(float4*)&yp_g[(size_t)bh * 8192 + (size_t)(2 * fbin) * 64 + 4 * d0] = outr;
  *(float4*)&yp_g[(size_t)bh * 8192 + (size_t)(2 * fbin + 1) * 64 + 4 * d0] = outi;
}

// ------------------------------------------------------------- irfft GEMM
// grid 512 = 64 bh * 8 lchunks(512 l) ; block 256
__global__ __launch_bounds__(256) void irfft_k(const float* __restrict__ yp_g,
                                               const float* __restrict__ bt_g,
                                               float* __restrict__ out) {
  int bh = blockIdx.x >> 3, lc = blockIdx.x & 7;
  int t = threadIdx.x;
  __shared__ float yp[128 * 64];
  __shared__ float bt[128 * 64];

  const float4* ysrc = (const float4*)(yp_g + (size_t)bh * 8192);
#pragma unroll
  for (int j = 0; j < 8; ++j) ((float4*)yp)[t + 256 * j] = ysrc[t + 256 * j];

  int d = t & 63, lg = t >> 6;
  float* obase = out + (size_t)bh * (LSEQ * DIM);

  for (int ti = 0; ti < 8; ++ti) {
    int lbase = lc * 512 + ti * 64;
    __syncthreads();
#pragma unroll
    for (int j = 0; j < 8; ++j) {
      int u4 = t + 256 * j;  // < 2048
      int kk = u4 >> 4, lo = u4 & 15;
      ((float4*)bt)[kk * 16 + lo] =
          ((const float4*)bt_g)[kk * 1024 + (lbase >> 2) + lo];
    }
    __syncthreads();
    float acc[16];
#pragma unroll
    for (int i = 0; i < 16; ++i) acc[i] = 0.0f;
    for (int kk = 0; kk < 128; ++kk) {
      float yv = yp[kk * 64 + d];
      const float* brow = &bt[kk * 64 + lg * 16];
#pragma unroll
      for (int i = 0; i < 16; ++i) acc[i] = fmaf(brow[i], yv, acc[i]);
    }
#pragma unroll
    for (int i = 0; i < 16; ++i)
      obase[(size_t)(lbase + lg * 16 + i) * 64 + d] = acc[i];
  }
}

extern "C" void kernel_launch(void* const* d_in, const int* in_sizes, int n_in,
                              void* d_out, int out_size, void* d_ws,
                              size_t ws_size, hipStream_t stream) {
  const float* q = (const float*)d_in[0];
  const float* k = (const float*)d_in[1];
  const float* v = (const float*)d_in[2];
  const int* iq = (const int*)d_in[3];
  const int* ik = (const int*)d_in[4];
  const int* iv = (const int*)d_in[5];
  float* ws = (float*)d_ws;
  float* ftpart = ws;                 // 3,145,728 floats
  float* yp = ws + 3145728;           // 524,288 floats
  float* bt = ws + 3670016;           // 524,288 floats
  float* out = (float*)d_out;

  hipLaunchKernelGGL(init_basis, dim3(2048), dim3(256), 0, stream, bt);
  hipLaunchKernelGGL(dft_gather, dim3(384), dim3(512), 0, stream, q, k, v, iq,
                     ik, iv, ftpart);
  hipLaunchKernelGGL(attn, dim3(256), dim3(256), 0, stream, ftpart, yp);
  hipLaunchKernelGGL(irfft_k, dim3(512), dim3(256), 0, stream, yp, bt, out);
}

// Round 3
// 266.614 us; speedup vs baseline: 1.7821x; 1.7821x over previous
//
#include <hip/hip_runtime.h>
#include <hip/hip_bf16.h>
#include <math.h>

#define LSEQ 4096
#define DIM 64
#define TWO_PI 6.28318530717958647692f

typedef __attribute__((ext_vector_type(8))) short bf16x8;
typedef __attribute__((ext_vector_type(4))) float f32x4;

// ws layout (bytes):
//   btT  bf16 [4096][128]            1,048,576 @ 0
//   ypt  bf16 [64 bh][64 d][128 k]   1,048,576 @ 1,048,576
//   ftQK fp32 [128 tbh][4][128][64] 16,777,216 @ 2,097,152
//   ftV  bf16 [64 bh][4][128][64]    4,194,304 @ 18,874,368
//   Whi  bf16 [3][128][4096]         3,145,728 @ 23,068,672
//   Wlo  bf16 [3][128][4096]         3,145,728 @ 26,214,400
//   total 29,360,128  (ws proven >= 31MB in R1)

__device__ __forceinline__ unsigned short f2bfu(float f) {
  __hip_bfloat16 h = __float2bfloat16(f);
  return *(unsigned short*)&h;
}
__device__ __forceinline__ float bfu2f(unsigned short h) {
  union { unsigned int u; float f; } z;
  z.u = ((unsigned int)h) << 16;
  return z.f;
}

// ---------------------------------------------------------------- init btT (irfft basis, bf16)
__global__ __launch_bounds__(256) void init_btT(unsigned short* __restrict__ btT) {
  int u = blockIdx.x * 256 + threadIdx.x;  // < 4096*128
  int l = u >> 7, kk = u & 127;
  int f = kk >> 1;
  float ang = (float)((f * l) & 4095) * (TWO_PI / 4096.0f);
  float s, c;
  sincosf(ang, &s, &c);
  float val = (kk & 1) ? -s : c;
  btT[u] = f2bfu(val);
}

// ---------------------------------------------------------------- init W hi/lo (DFT twiddles)
__global__ __launch_bounds__(256) void init_w(unsigned short* __restrict__ whi,
                                              unsigned short* __restrict__ wlo,
                                              const int* __restrict__ iq,
                                              const int* __restrict__ ik,
                                              const int* __restrict__ iv) {
  int u = blockIdx.x * 256 + threadIdx.x;  // < 3*128*4096
  int tensor = u >> 19;
  int rem = u & 524287;
  int row = rem >> 12;
  int l = rem & 4095;
  int m = row & 63, reim = row >> 6;
  const int* idx = (tensor == 0 ? iq : tensor == 1 ? ik : iv);
  int f = idx[m];
  float ang = (float)((f * l) & 4095) * (TWO_PI / 4096.0f);
  float s, c;
  sincosf(ang, &s, &c);
  float val = reim ? -s : c;  // e^{-i t}: re=cos, im=-sin
  __hip_bfloat16 hb = __float2bfloat16(val);
  float fh = __bfloat162float(hb);
  whi[u] = *(unsigned short*)&hb;
  wlo[u] = f2bfu(val - fh);
}

// ---------------------------------------------------------------- MFMA DFT (split-bf16)
// grid 768 = 3 tensor * 64 bh * 4 Kpart ; block 256 (4 waves)
__global__ __launch_bounds__(256) void dft_mfma(
    const float* __restrict__ q, const float* __restrict__ k,
    const float* __restrict__ v, const unsigned short* __restrict__ whi,
    const unsigned short* __restrict__ wlo, float* __restrict__ ftQK,
    unsigned short* __restrict__ ftV) {
  int b = blockIdx.x;
  int tensor = b >> 8;
  int bh = (b >> 2) & 63;
  int part = b & 3;
  const float* x =
      (tensor == 0 ? q : tensor == 1 ? k : v) + (size_t)bh * (LSEQ * DIM);
  const unsigned short* wh = whi + (size_t)tensor * 524288;
  const unsigned short* wl = wlo + (size_t)tensor * 524288;

  int t = threadIdx.x;
  int lane = t & 63, w = t >> 6;
  int l15 = lane & 15, qd = lane >> 4;
  int xd = t & 63, xseg = t >> 6;

  __shared__ __align__(16) unsigned short Wb[128 * 72];
  __shared__ __align__(16) unsigned short Xh[64 * 72];
  __shared__ __align__(16) unsigned short Xl[64 * 72];

  f32x4 acc[2][4];
#pragma unroll
  for (int mt = 0; mt < 2; ++mt)
#pragma unroll
    for (int nt = 0; nt < 4; ++nt) acc[mt][nt] = (f32x4){0.f, 0.f, 0.f, 0.f};

  bool split = (tensor != 2);
  int k0 = part * 1024;
  for (int ch = 0; ch < 16; ++ch) {
    int lc = k0 + ch * 64;
    __syncthreads();
    // stage Whi: 128 rows x 64 bf16
#pragma unroll
    for (int j = 0; j < 4; ++j) {
      int u = t + 256 * j;
      int row = u >> 3, seg = u & 7;
      *(float4*)&Wb[row * 72 + seg * 8] =
          *(const float4*)&wh[(size_t)row * 4096 + lc + seg * 8];
    }
    // transposed coalesced X load + hi/lo split -> Xh/Xl [d][l]
    {
      float xv[16];
#pragma unroll
      for (int i = 0; i < 16; ++i)
        xv[i] = x[(size_t)(lc + xseg * 16 + i) * 64 + xd];
      __align__(16) unsigned short hs[16];
      __align__(16) unsigned short ls[16];
#pragma unroll
      for (int i = 0; i < 16; ++i) {
        __hip_bfloat16 hb = __float2bfloat16(xv[i]);
        hs[i] = *(unsigned short*)&hb;
        float fh = __bfloat162float(hb);
        ls[i] = f2bfu(xv[i] - fh);
      }
      *(bf16x8*)&Xh[xd * 72 + xseg * 16] = *(bf16x8*)&hs[0];
      *(bf16x8*)&Xh[xd * 72 + xseg * 16 + 8] = *(bf16x8*)&hs[8];
      *(bf16x8*)&Xl[xd * 72 + xseg * 16] = *(bf16x8*)&ls[0];
      *(bf16x8*)&Xl[xd * 72 + xseg * 16 + 8] = *(bf16x8*)&ls[8];
    }
    __syncthreads();
    // Whi*(Xhi+Xlo)
#pragma unroll
    for (int ks = 0; ks < 2; ++ks) {
      bf16x8 af[2], bh_[4], bl_[4];
#pragma unroll
      for (int mt = 0; mt < 2; ++mt)
        af[mt] = *(const bf16x8*)&Wb[((w * 2 + mt) * 16 + l15) * 72 + ks * 32 +
                                     qd * 8];
#pragma unroll
      for (int nt = 0; nt < 4; ++nt) {
        bh_[nt] = *(const bf16x8*)&Xh[(nt * 16 + l15) * 72 + ks * 32 + qd * 8];
        bl_[nt] = *(const bf16x8*)&Xl[(nt * 16 + l15) * 72 + ks * 32 + qd * 8];
      }
#pragma unroll
      for (int mt = 0; mt < 2; ++mt)
#pragma unroll
        for (int nt = 0; nt < 4; ++nt) {
          acc[mt][nt] = __builtin_amdgcn_mfma_f32_16x16x32_bf16(
              af[mt], bh_[nt], acc[mt][nt], 0, 0, 0);
          acc[mt][nt] = __builtin_amdgcn_mfma_f32_16x16x32_bf16(
              af[mt], bl_[nt], acc[mt][nt], 0, 0, 0);
        }
    }
    if (split) {
      __syncthreads();
      // stage Wlo over Wb
#pragma unroll
      for (int j = 0; j < 4; ++j) {
        int u = t + 256 * j;
        int row = u >> 3, seg = u & 7;
        *(float4*)&Wb[row * 72 + seg * 8] =
            *(const float4*)&wl[(size_t)row * 4096 + lc + seg * 8];
      }
      __syncthreads();
      // Wlo*Xhi
#pragma unroll
      for (int ks = 0; ks < 2; ++ks) {
        bf16x8 af[2], bh_[4];
#pragma unroll
        for (int mt = 0; mt < 2; ++mt)
          af[mt] = *(const bf16x8*)&Wb[((w * 2 + mt) * 16 + l15) * 72 +
                                       ks * 32 + qd * 8];
#pragma unroll
        for (int nt = 0; nt < 4; ++nt)
          bh_[nt] =
              *(const bf16x8*)&Xh[(nt * 16 + l15) * 72 + ks * 32 + qd * 8];
#pragma unroll
        for (int mt = 0; mt < 2; ++mt)
#pragma unroll
          for (int nt = 0; nt < 4; ++nt)
            acc[mt][nt] = __builtin_amdgcn_mfma_f32_16x16x32_bf16(
                af[mt], bh_[nt], acc[mt][nt], 0, 0, 0);
      }
    }
  }
  // epilogue: C/D layout col=lane&15, row=(lane>>4)*4+reg
  if (tensor < 2) {
    float* o = ftQK + ((size_t)(tensor * 64 + bh) * 4 + part) * 8192;
#pragma unroll
    for (int mt = 0; mt < 2; ++mt) {
      int row0 = (w * 2 + mt) * 16 + qd * 4;
#pragma unroll
      for (int nt = 0; nt < 4; ++nt) {
        int col = nt * 16 + l15;
#pragma unroll
        for (int r = 0; r < 4; ++r) o[(row0 + r) * 64 + col] = acc[mt][nt][r];
      }
    }
  } else {
    unsigned short* o = ftV + ((size_t)bh * 4 + part) * 8192;
#pragma unroll
    for (int mt = 0; mt < 2; ++mt) {
      int row0 = (w * 2 + mt) * 16 + qd * 4;
#pragma unroll
      for (int nt = 0; nt < 4; ++nt) {
        int col = nt * 16 + l15;
#pragma unroll
        for (int r = 0; r < 4; ++r)
          o[(row0 + r) * 64 + col] = f2bfu(acc[mt][nt][r]);
      }
    }
  }
}

// ---------------------------------------------------------------- attention
// grid 256 = 64 bh * 4 mq ; block 256. Sums 4 K-parts; writes ypT bf16 [bh][d][128k].
#define FST 132
__global__ __launch_bounds__(256) void attn(const float* __restrict__ ftQK,
                                            const unsigned short* __restrict__ ftV,
                                            unsigned short* __restrict__ ypt) {
  int bh = blockIdx.x >> 2, mq = blockIdx.x & 3;
  int t = threadIdx.x;

  __shared__ float qf[16 * FST];
  __shared__ float kf[64 * FST];
  __shared__ float vf[64 * FST];
  __shared__ float S[16 * FST];

  const float* qb = ftQK + (size_t)bh * 4 * 8192;
  const float* kb = ftQK + (size_t)(64 + bh) * 4 * 8192;
  const unsigned short* vb = ftV + (size_t)bh * 4 * 8192;

  // stage K (fp32 x4 parts), V (bf16 x4 parts)
#pragma unroll
  for (int j = 0; j < 8; ++j) {
    int u4 = t + 256 * j;  // < 2048
    int row = u4 >> 4, dq = u4 & 15;
    float4 ksum = make_float4(0.f, 0.f, 0.f, 0.f);
    float vsum[4] = {0.f, 0.f, 0.f, 0.f};
#pragma unroll
    for (int p = 0; p < 4; ++p) {
      float4 a = *(const float4*)&kb[(size_t)p * 8192 + row * 64 + dq * 4];
      ksum.x += a.x; ksum.y += a.y; ksum.z += a.z; ksum.w += a.w;
      ushort4 vv = *(const ushort4*)&vb[(size_t)p * 8192 + row * 64 + dq * 4];
      vsum[0] += bfu2f(vv.x); vsum[1] += bfu2f(vv.y);
      vsum[2] += bfu2f(vv.z); vsum[3] += bfu2f(vv.w);
    }
    int mm = row & 63, reim = row >> 6;
    int base = mm * FST + reim;
    kf[base + 2 * (4 * dq + 0)] = ksum.x;
    kf[base + 2 * (4 * dq + 1)] = ksum.y;
    kf[base + 2 * (4 * dq + 2)] = ksum.z;
    kf[base + 2 * (4 * dq + 3)] = ksum.w;
    vf[base + 2 * (4 * dq + 0)] = vsum[0];
    vf[base + 2 * (4 * dq + 1)] = vsum[1];
    vf[base + 2 * (4 * dq + 2)] = vsum[2];
    vf[base + 2 * (4 * dq + 3)] = vsum[3];
  }
  // stage Q rows mq*16..+15
#pragma unroll
  for (int j = 0; j < 2; ++j) {
    int u4 = t + 256 * j;  // < 512
    int rl = u4 >> 4, dq = u4 & 15;
    int i = rl & 15, reim = rl >> 4;
    int row = reim * 64 + mq * 16 + i;
    float4 qsum = make_float4(0.f, 0.f, 0.f, 0.f);
#pragma unroll
    for (int p = 0; p < 4; ++p) {
      float4 a = *(const float4*)&qb[(size_t)p * 8192 + row * 64 + dq * 4];
      qsum.x += a.x; qsum.y += a.y; qsum.z += a.z; qsum.w += a.w;
    }
    int base = i * FST + reim;
    qf[base + 2 * (4 * dq + 0)] = qsum.x;
    qf[base + 2 * (4 * dq + 1)] = qsum.y;
    qf[base + 2 * (4 * dq + 2)] = qsum.z;
    qf[base + 2 * (4 * dq + 3)] = qsum.w;
  }
  __syncthreads();

  int m = t >> 4;
  int n0 = t & 15;
#pragma unroll
  for (int nn = 0; nn < 4; ++nn) {
    int n = n0 + 16 * nn;
    float xr = 0.0f, xi = 0.0f;
    for (int d2 = 0; d2 < 32; ++d2) {
      float4 qv = *(const float4*)&qf[m * FST + 4 * d2];
      float4 kv = *(const float4*)&kf[n * FST + 4 * d2];
      xr = fmaf(qv.x, kv.x, xr); xr = fmaf(-qv.y, kv.y, xr);
      xi = fmaf(qv.x, kv.y, xi); xi = fmaf(qv.y, kv.x, xi);
      xr = fmaf(qv.z, kv.z, xr); xr = fmaf(-qv.w, kv.w, xr);
      xi = fmaf(qv.z, kv.w, xi); xi = fmaf(qv.w, kv.z, xi);
    }
    float x = xr * 0.125f, y = xi * 0.125f;
    float tr, tim;
    if (fabsf(x) > 40.0f) {
      tr = x > 0.0f ? 1.0f : -1.0f;
      tim = 0.0f;
    } else {
      float sh = sinhf(2.0f * x), ch = coshf(2.0f * x);
      float sn, cn;
      sincosf(2.0f * y, &sn, &cn);
      float den = ch + cn;
      tr = sh / den;
      tim = sn / den;
    }
    S[m * FST + 2 * n] = tr;
    S[m * FST + 2 * n + 1] = tim;
  }
  __syncthreads();

  int d0 = t & 15;
  float ar4[4] = {0, 0, 0, 0}, ai4[4] = {0, 0, 0, 0};
  for (int n = 0; n < 64; ++n) {
    float sr_ = S[m * FST + 2 * n];
    float si_ = S[m * FST + 2 * n + 1];
    float4 va = *(const float4*)&vf[n * FST + 8 * d0];
    float4 vb2 = *(const float4*)&vf[n * FST + 8 * d0 + 4];
    ar4[0] = fmaf(sr_, va.x, ar4[0]); ar4[0] = fmaf(-si_, va.y, ar4[0]);
    ai4[0] = fmaf(sr_, va.y, ai4[0]); ai4[0] = fmaf(si_, va.x, ai4[0]);
    ar4[1] = fmaf(sr_, va.z, ar4[1]); ar4[1] = fmaf(-si_, va.w, ar4[1]);
    ai4[1] = fmaf(sr_, va.w, ai4[1]); ai4[1] = fmaf(si_, va.z, ai4[1]);
    ar4[2] = fmaf(sr_, vb2.x, ar4[2]); ar4[2] = fmaf(-si_, vb2.y, ar4[2]);
    ai4[2] = fmaf(sr_, vb2.y, ai4[2]); ai4[2] = fmaf(si_, vb2.x, ai4[2]);
    ar4[3] = fmaf(sr_, vb2.z, ar4[3]); ar4[3] = fmaf(-si_, vb2.w, ar4[3]);
    ai4[3] = fmaf(sr_, vb2.w, ai4[3]); ai4[3] = fmaf(si_, vb2.z, ai4[3]);
  }
  int fbin = mq * 16 + m;
  float cf = (fbin == 0 ? 1.0f : 2.0f) / 4096.0f;
#pragma unroll
  for (int c = 0; c < 4; ++c) {
    int d = 4 * d0 + c;
    ypt[((size_t)bh * 64 + d) * 128 + 2 * fbin] = f2bfu(cf * ar4[c]);
    ypt[((size_t)bh * 64 + d) * 128 + 2 * fbin + 1] = f2bfu(cf * ai4[c]);
  }
}

// ---------------------------------------------------------------- irfft (bf16 MFMA GEMM)
// grid 4096 = 64 bh * 64 lchunk ; block 256 (4 waves). out[l][d] = sum_k btT[l][k]*ypt[d][k]
__global__ __launch_bounds__(256) void irfft_mfma(
    const unsigned short* __restrict__ ypt,
    const unsigned short* __restrict__ btT, float* __restrict__ out) {
  int bh = blockIdx.x >> 6, lc = blockIdx.x & 63;
  int t = threadIdx.x;
  int lane = t & 63, w = t >> 6;
  int l15 = lane & 15, qd = lane >> 4;

  __shared__ __align__(16) unsigned short A[2 * 64 * 72];  // [khalf][l][k64]
  __shared__ __align__(16) unsigned short Bm[2 * 64 * 72]; // [khalf][d][k64]

#pragma unroll
  for (int j = 0; j < 4; ++j) {
    int u = t + 256 * j;  // < 1024
    int row = u >> 4, seg = u & 15;
    int kh = seg >> 3, s8 = seg & 7;
    *(float4*)&A[kh * 4608 + row * 72 + s8 * 8] =
        *(const float4*)&btT[(size_t)(lc * 64 + row) * 128 + seg * 8];
    *(float4*)&Bm[kh * 4608 + row * 72 + s8 * 8] =
        *(const float4*)&ypt[(size_t)(bh * 64 + row) * 128 + seg * 8];
  }
  __syncthreads();

  f32x4 acc[4];
#pragma unroll
  for (int nt = 0; nt < 4; ++nt) acc[nt] = (f32x4){0.f, 0.f, 0.f, 0.f};

#pragma unroll
  for (int kh = 0; kh < 2; ++kh)
#pragma unroll
    for (int ks = 0; ks < 2; ++ks) {
      bf16x8 af =
          *(const bf16x8*)&A[kh * 4608 + (w * 16 + l15) * 72 + ks * 32 + qd * 8];
#pragma unroll
      for (int nt = 0; nt < 4; ++nt) {
        bf16x8 bf =
            *(const bf16x8*)&Bm[kh * 4608 + (nt * 16 + l15) * 72 + ks * 32 +
                                qd * 8];
        acc[nt] = __builtin_amdgcn_mfma_f32_16x16x32_bf16(af, bf, acc[nt], 0, 0, 0);
      }
    }

  float* obase = out + ((size_t)bh * 4096 + lc * 64) * 64;
  int row0 = w * 16 + qd * 4;
#pragma unroll
  for (int nt = 0; nt < 4; ++nt) {
    int col = nt * 16 + l15;
#pragma unroll
    for (int r = 0; r < 4; ++r) obase[(row0 + r) * 64 + col] = acc[nt][r];
  }
}

extern "C" void kernel_launch(void* const* d_in, const int* in_sizes, int n_in,
                              void* d_out, int out_size, void* d_ws,
                              size_t ws_size, hipStream_t stream) {
  const float* q = (const float*)d_in[0];
  const float* k = (const float*)d_in[1];
  const float* v = (const float*)d_in[2];
  const int* iq = (const int*)d_in[3];
  const int* ik = (const int*)d_in[4];
  const int* iv = (const int*)d_in[5];
  char* ws = (char*)d_ws;
  unsigned short* btT = (unsigned short*)ws;
  unsigned short* ypt = (unsigned short*)(ws + 1048576);
  float* ftQK = (float*)(ws + 2097152);
  unsigned short* ftV = (unsigned short*)(ws + 18874368);
  unsigned short* whi = (unsigned short*)(ws + 23068672);
  unsigned short* wlo = (unsigned short*)(ws + 26214400);
  float* out = (float*)d_out;

  hipLaunchKernelGGL(init_btT, dim3(2048), dim3(256), 0, stream, btT);
  hipLaunchKernelGGL(init_w, dim3(6144), dim3(256), 0, stream, whi, wlo, iq,
                     ik, iv);
  hipLaunchKernelGGL(dft_mfma, dim3(768), dim3(256), 0, stream, q, k, v, whi,
                     wlo, ftQK, ftV);
  hipLaunchKernelGGL(attn, dim3(256), dim3(256), 0, stream, ftQK, ftV, ypt);
  hipLaunchKernelGGL(irfft_mfma, dim3(4096), dim3(256), 0, stream, ypt, btT,
                     out);
}